// Round 6
// baseline (332.337 us; speedup 1.0000x reference)
//
#include <hip/hip_runtime.h>
#include <hip/hip_bf16.h>

#define B_   32
#define CIN  96
#define COUT 96
#define NP   3136
#define NE   8
#define HIDD 576

typedef short bf16x8 __attribute__((ext_vector_type(8)));
typedef float f32x4 __attribute__((ext_vector_type(4)));

__device__ __forceinline__ unsigned short f2bf(float f) {
  __hip_bfloat16 h = __float2bfloat16(f);
  unsigned short u; __builtin_memcpy(&u, &h, 2); return u;
}
__device__ __forceinline__ float bf2f(unsigned short u) {
  unsigned int v = ((unsigned int)u) << 16;
  float f; __builtin_memcpy(&f, &v, 4); return f;
}
__device__ __forceinline__ float u2f(unsigned int v) {
  float f; __builtin_memcpy(&f, &v, 4); return f;
}

// ---------------- kernel 1: transpose x -> x_t[b][p][c] bf16, + channel sums --
__global__ __launch_bounds__(256) void k_transpose(const float* __restrict__ x,
                                                   unsigned short* __restrict__ xt,
                                                   float* __restrict__ xmean) {
  __shared__ float tile[CIN][65];
  int bi = blockIdx.x; int b = bi / 49, pt = bi % 49; int p0 = pt * 64;
  int t = threadIdx.x;
  for (int j = t; j < CIN * 64; j += 256) {
    int c = j >> 6, pi = j & 63;
    tile[c][pi] = x[((size_t)(b * CIN + c)) * NP + p0 + pi];
  }
  __syncthreads();
  if (t < CIN) {
    float s = 0.f;
    for (int i = 0; i < 64; ++i) s += tile[t][i];
    atomicAdd(xmean + b * CIN + t, s);
  }
  for (int j = t; j < 64 * CIN; j += 256) {
    int p = j / CIN, c = j % CIN;
    xt[((size_t)(b * NP + p0 + p)) * CIN + c] = f2bf(tile[c][p]);
  }
}

// ---------------- kernel 2: routers r1 (expand) and r_blk (project) ----------
__global__ __launch_bounds__(64) void k_router1(const float* __restrict__ xmean,
    const float* __restrict__ wr1, const float* __restrict__ br1,
    const float* __restrict__ wr3, const float* __restrict__ br3,
    float* __restrict__ r1, float* __restrict__ rblk) {
  int bi = blockIdx.x; int lane = threadIdx.x;
  const float* wr; const float* br; float* dst; int id;
  if (bi < 256) { wr = wr1; br = br1; dst = r1;   id = bi; }
  else          { wr = wr3; br = br3; dst = rblk; id = bi - 256; }
  int b = id >> 3, e = id & 7;
  float s = 0.f;
  for (int c = lane; c < CIN; c += 64)
    s += xmean[b * CIN + c] * (1.0f / NP) * wr[e * CIN + c];
  s += __shfl_xor(s, 1);  s += __shfl_xor(s, 2);  s += __shfl_xor(s, 4);
  s += __shfl_xor(s, 8);  s += __shfl_xor(s, 16); s += __shfl_xor(s, 32);
  if (lane == 0) dst[id] = 1.0f / (1.0f + __expf(-(s + br[e])));
}

// ---------------- kernel 3: BN scale/bias precompute -------------------------
__global__ __launch_bounds__(256) void k_bnprep(
    const float* g1, const float* bt1, const float* m1, const float* v1,
    const float* g2, const float* bt2, const float* m2, const float* v2,
    const float* g3, const float* bt3, const float* m3, const float* v3,
    float* sc1, float* bi1, float* sc2, float* bi2, float* sc3, float* bi3) {
  int i = blockIdx.x * 256 + threadIdx.x;
  if (i < HIDD) {
    float s = g1[i] * rsqrtf(v1[i] + 1e-5f); sc1[i] = s; bi1[i] = bt1[i] - m1[i] * s;
  } else if (i < 2 * HIDD) {
    int c = i - HIDD;
    float s = g2[c] * rsqrtf(v2[c] + 1e-5f); sc2[c] = s; bi2[c] = bt2[c] - m2[c] * s;
  } else if (i < 2 * HIDD + COUT) {
    int c = i - 2 * HIDD;
    float s = g3[c] * rsqrtf(v3[c] + 1e-5f); sc3[c] = s; bi3[c] = bt3[c] - m3[c] * s;
  }
}

// ---------------- kernel 4: mix expert weights -> bf16 -----------------------
__global__ __launch_bounds__(256) void k_mixw(
    const float* __restrict__ w1, const float* __restrict__ r1, unsigned short* __restrict__ w1c,
    const float* __restrict__ w3, const float* __restrict__ rblk, unsigned short* __restrict__ w3c) {
  __shared__ float rsh[256];
  int bi = blockIdx.x; int t = threadIdx.x;
  const float* w; const float* r; unsigned short* dst; int oc0;
  if (bi < 216) { w = w1; r = r1;   dst = w1c; oc0 = bi * 256; }
  else          { w = w3; r = rblk; dst = w3c; oc0 = (bi - 216) * 256; }
  rsh[t] = r[t];
  __syncthreads();
  int oc = oc0 + t;
  float wv[NE];
#pragma unroll
  for (int e = 0; e < NE; ++e) wv[e] = w[(size_t)e * 55296 + oc];
  for (int b = 0; b < B_; ++b) {
    float a = 0.f;
#pragma unroll
    for (int e = 0; e < NE; ++e) a += rsh[b * 8 + e] * wv[e];
    dst[(size_t)b * 55296 + oc] = f2bf(a);
  }
}

// ---------------- kernel 5: expand GEMM, o-tile 192, y in [b][p][h] ----------
// y2[b][p][o] = relu6(bn1( sum_c w1c[b][o][c] * x_t[b][p][c] ))
// One Bs staging serves 3 o-subtiles: 36 MFMA/wave per barrier-pair.
__global__ __launch_bounds__(256, 3) void k_expand3(const unsigned short* __restrict__ xt,
    const unsigned short* __restrict__ w1c, const float* __restrict__ sc1,
    const float* __restrict__ bi1, unsigned short* __restrict__ y2,
    float* __restrict__ ysum) {
  __shared__ unsigned short As[192 * 104];   // w1c tile; reused as T[3][64][72]
  __shared__ unsigned short Bs[64 * 104];    // xt tile
  int t = threadIdx.x;
  int p0 = blockIdx.x * 64, o0 = blockIdx.y * 192, b = blockIdx.z;
  const unsigned short* ag = w1c + (size_t)b * 55296 + (size_t)o0 * 96;
  const unsigned short* bg = xt + ((size_t)b * NP + p0) * 96;
  for (int j = t; j < 2304; j += 256) {
    int r = j / 12, ch = j % 12;
    *(int4*)(As + r * 104 + ch * 8) = *(const int4*)(ag + r * 96 + ch * 8);
  }
  for (int j = t; j < 768; j += 256) {
    int r = j / 12, ch = j % 12;
    *(int4*)(Bs + r * 104 + ch * 8) = *(const int4*)(bg + r * 96 + ch * 8);
  }
  __syncthreads();
  int lane = t & 63, wv = t >> 6;
  int m = lane & 15, q = lane >> 4;
  f32x4 acc[3][4];
#pragma unroll
  for (int ot = 0; ot < 3; ++ot)
#pragma unroll
    for (int nt = 0; nt < 4; ++nt) acc[ot][nt] = 0.f;
#pragma unroll
  for (int kk = 0; kk < 3; ++kk) {
    bf16x8 af[3];
#pragma unroll
    for (int ot = 0; ot < 3; ++ot)
      af[ot] = *(const bf16x8*)(As + (ot * 64 + wv * 16 + m) * 104 + kk * 32 + q * 8);
#pragma unroll
    for (int nt = 0; nt < 4; ++nt) {
      bf16x8 bfb = *(const bf16x8*)(Bs + (nt * 16 + m) * 104 + kk * 32 + q * 8);
#pragma unroll
      for (int ot = 0; ot < 3; ++ot)
        acc[ot][nt] = __builtin_amdgcn_mfma_f32_16x16x32_bf16(af[ot], bfb, acc[ot][nt], 0, 0, 0);
    }
  }
  __syncthreads();   // all LDS reads done; As reusable as T
  unsigned short* T = As;   // 3 tiles of [64][72] u16 = 13824 u16 < 19968
#pragma unroll
  for (int ot = 0; ot < 3; ++ot) {
    float sc[4], bb[4];
#pragma unroll
    for (int i = 0; i < 4; ++i) {
      int o = o0 + ot * 64 + wv * 16 + q * 4 + i;
      sc[i] = sc1[o]; bb[i] = bi1[o];
    }
    float rs[4] = {0.f, 0.f, 0.f, 0.f};
#pragma unroll
    for (int nt = 0; nt < 4; ++nt) {
      unsigned short pk[4];
#pragma unroll
      for (int i = 0; i < 4; ++i) {
        float v = acc[ot][nt][i] * sc[i] + bb[i];
        v = fminf(fmaxf(v, 0.f), 6.f);
        rs[i] += v;
        pk[i] = f2bf(v);
      }
      uint2 pv; __builtin_memcpy(&pv, pk, 8);
      *(uint2*)(T + ot * 4608 + (nt * 16 + m) * 72 + wv * 16 + q * 4) = pv;
    }
#pragma unroll
    for (int i = 0; i < 4; ++i) {
      float r = rs[i];
      r += __shfl_xor(r, 1); r += __shfl_xor(r, 2);
      r += __shfl_xor(r, 4); r += __shfl_xor(r, 8);
      if (m == 0) atomicAdd(ysum + b * HIDD + o0 + ot * 64 + wv * 16 + q * 4 + i, r);
    }
  }
  __syncthreads();
  for (int j = t; j < 1536; j += 256) {
    int ot = j >> 9, rr = (j >> 3) & 63, ch = j & 7;
    *(int4*)(y2 + ((size_t)(b * NP + p0 + rr)) * 576 + o0 + ot * 64 + ch * 8) =
        *(const int4*)(T + ot * 4608 + rr * 72 + ch * 8);
  }
}

// ---------------- kernel 6: router r2 (depthwise) ----------------------------
__global__ __launch_bounds__(64) void k_router2(const float* __restrict__ ysum,
    const float* __restrict__ wr2, const float* __restrict__ br2, float* __restrict__ r2) {
  int id = blockIdx.x; int lane = threadIdx.x;
  int b = id >> 3, e = id & 7;
  float s = 0.f;
  for (int h = lane; h < HIDD; h += 64)
    s += ysum[b * HIDD + h] * (1.0f / NP) * wr2[e * HIDD + h];
  s += __shfl_xor(s, 1);  s += __shfl_xor(s, 2);  s += __shfl_xor(s, 4);
  s += __shfl_xor(s, 8);  s += __shfl_xor(s, 16); s += __shfl_xor(s, 32);
  if (lane == 0) r2[id] = 1.0f / (1.0f + __expf(-(s + br2[e])));
}

// ---------------- kernel 6b: premix depthwise taps, layout kwt[b][tap][c] ----
__global__ __launch_bounds__(256) void k_kwmix2(const float* __restrict__ r2,
    const float* __restrict__ w2, const float* __restrict__ sc2,
    const float* __restrict__ bi2, float* __restrict__ kwt) {
  int i = blockIdx.x * 256 + threadIdx.x;
  if (i >= B_ * HIDD) return;
  int b = i / HIDD, c = i - b * HIDD;
  float rr[NE];
#pragma unroll
  for (int e = 0; e < NE; ++e) rr[e] = r2[b * 8 + e];
  float sc = sc2[c];
  float* dst = kwt + (size_t)b * 5760 + c;
#pragma unroll
  for (int k = 0; k < 9; ++k) {
    float s = 0.f;
#pragma unroll
    for (int e = 0; e < NE; ++e) s += rr[e] * w2[((size_t)e * HIDD + c) * 9 + k];
    dst[k * 576] = s * sc;
  }
  dst[9 * 576] = bi2[c];
}

// ---------------- kernel 7: depthwise 3x3 — 4ch x 2 rows x 28 cols / thread --
// w split in halves vs round-5 (2x waves for latency hiding; col halo +7%).
__device__ __forceinline__ f32x4 cvt4(uint2 v) {
  f32x4 r;
  r[0] = u2f(v.x << 16); r[1] = u2f(v.x & 0xffff0000u);
  r[2] = u2f(v.y << 16); r[3] = u2f(v.y & 0xffff0000u);
  return r;
}
__device__ __forceinline__ uint2 pack4(f32x4 v) {
  uint2 r;
  r.x = (unsigned)f2bf(v[0]) | ((unsigned)f2bf(v[1]) << 16);
  r.y = (unsigned)f2bf(v[2]) | ((unsigned)f2bf(v[3]) << 16);
  return r;
}
__device__ __forceinline__ f32x4 clamp6(f32x4 v) {
#pragma unroll
  for (int i = 0; i < 4; ++i) v[i] = fminf(fmaxf(v[i], 0.f), 6.f);
  return v;
}

__global__ __launch_bounds__(256) void k_dwise5(const unsigned short* __restrict__ y2,
    const float* __restrict__ kwt, unsigned short* __restrict__ z2) {
  int id = blockIdx.x * 256 + threadIdx.x;   // 32 b * 28 hp * 2 wh * 144 cq = 258048
  int cg = id % 144; int rest = id / 144;
  int wh = rest & 1; rest >>= 1;
  int hp = rest % 28; int b = rest / 28;
  int c = cg * 4, h0 = hp * 2, wsrt = wh * 28;
  const float* kp = kwt + (size_t)b * 5760 + c;
  f32x4 tk[9], tb;
#pragma unroll
  for (int k = 0; k < 9; ++k) tk[k] = *(const f32x4*)(kp + k * 576);
  tb = *(const f32x4*)(kp + 9 * 576);
  bool ok0 = (hp > 0), ok3 = (hp < 27);
  int r0 = ok0 ? (h0 - 1) : h0;
  int r3 = ok3 ? (h0 + 2) : (h0 + 1);
  const unsigned short* rowp[4];
  rowp[0] = y2 + ((size_t)(b * NP + r0 * 56)) * 576 + c;
  rowp[1] = y2 + ((size_t)(b * NP + h0 * 56)) * 576 + c;
  rowp[2] = y2 + ((size_t)(b * NP + (h0 + 1) * 56)) * 576 + c;
  rowp[3] = y2 + ((size_t)(b * NP + r3 * 56)) * 576 + c;
  bool rok[4] = {ok0, true, true, ok3};
  unsigned short* zr0 = z2 + ((size_t)(b * NP + h0 * 56)) * 576 + c;
  unsigned short* zr1 = zr0 + (size_t)56 * 576;

  f32x4 P[4], C[4], N[4];

#define LOADCOL(D, col) do {                                           \
    _Pragma("unroll") for (int j = 0; j < 4; ++j) {                    \
      uint2 raw; raw.x = 0u; raw.y = 0u;                               \
      if ((unsigned)(col) < 56u && rok[j])                             \
        raw = *(const uint2*)(rowp[j] + (size_t)(col) * 576);          \
      D[j] = cvt4(raw);                                                \
    } } while (0)

#define DSTEP(PP, CC, NN, wcur) do {                                   \
    f32x4 o0 = tb, o1 = tb;                                            \
    _Pragma("unroll") for (int jj = 0; jj < 3; ++jj) {                 \
      o0 += PP[jj] * tk[jj * 3] + CC[jj] * tk[jj * 3 + 1] + NN[jj] * tk[jj * 3 + 2]; \
      o1 += PP[jj + 1] * tk[jj * 3] + CC[jj + 1] * tk[jj * 3 + 1] + NN[jj + 1] * tk[jj * 3 + 2]; \
    }                                                                  \
    *(uint2*)(zr0 + (size_t)(wcur) * 576) = pack4(clamp6(o0));         \
    *(uint2*)(zr1 + (size_t)(wcur) * 576) = pack4(clamp6(o1));         \
    LOADCOL(PP, (wcur) + 2);                                           \
  } while (0)

  LOADCOL(P, wsrt - 1);
  LOADCOL(C, wsrt);
  LOADCOL(N, wsrt + 1);
  // 28 outputs: 9 unrolled triples + 1 tail (roles realign every 3 steps)
  for (int w = wsrt; w < wsrt + 27; w += 3) {
    DSTEP(P, C, N, w);
    DSTEP(C, N, P, w + 1);
    DSTEP(N, P, C, w + 2);
  }
  DSTEP(P, C, N, wsrt + 27);
#undef DSTEP
#undef LOADCOL
}

// ---------------- kernel 8: project GEMM + BN + residual (z in [p][h]) -------
__global__ __launch_bounds__(384) void k_project4(const unsigned short* __restrict__ z2,
    const unsigned short* __restrict__ w3c, const float* __restrict__ sc3,
    const float* __restrict__ bi3, const float* __restrict__ x, float* __restrict__ out) {
  __shared__ unsigned short As[96 * 72];
  __shared__ unsigned short Bs[112 * 72];
  int t = threadIdx.x;
  int p0 = blockIdx.x * 112, b = blockIdx.z;
  const unsigned short* ag = w3c + (size_t)b * 55296;
  const unsigned short* zb = z2 + ((size_t)(b * NP + p0)) * 576;
  int lane = t & 63, wv = t >> 6;
  int m = lane & 15, q = lane >> 4;
  f32x4 acc[7];
#pragma unroll
  for (int nt = 0; nt < 7; ++nt) acc[nt] = 0.f;
  for (int c0 = 0; c0 < HIDD; c0 += 64) {
    __syncthreads();
    for (int j = t; j < 768; j += 384) {
      int r = j >> 3, ch = j & 7;
      *(int4*)(As + r * 72 + ch * 8) = *(const int4*)(ag + (size_t)r * 576 + c0 + ch * 8);
    }
    for (int j = t; j < 896; j += 384) {
      int r = j >> 3, ch = j & 7;
      *(int4*)(Bs + r * 72 + ch * 8) = *(const int4*)(zb + (size_t)r * 576 + c0 + ch * 8);
    }
    __syncthreads();
#pragma unroll
    for (int kk = 0; kk < 2; ++kk) {
      bf16x8 af = *(const bf16x8*)(As + (wv * 16 + m) * 72 + kk * 32 + q * 8);
#pragma unroll
      for (int nt = 0; nt < 7; ++nt) {
        bf16x8 bfb = *(const bf16x8*)(Bs + (nt * 16 + m) * 72 + kk * 32 + q * 8);
        acc[nt] = __builtin_amdgcn_mfma_f32_16x16x32_bf16(af, bfb, acc[nt], 0, 0, 0);
      }
    }
  }
#pragma unroll
  for (int i = 0; i < 4; ++i) {
    int o = wv * 16 + q * 4 + i;
    float sc = sc3[o], bb = bi3[o];
    size_t base = ((size_t)(b * COUT + o)) * NP + p0;
#pragma unroll
    for (int nt = 0; nt < 7; ++nt) {
      float v = acc[nt][i] * sc + bb + x[base + nt * 16 + m];
      out[base + nt * 16 + m] = v;
    }
  }
}

// ---------------- workspace layout (bytes) -----------------------------------
#define OFF_XT    ((size_t)0)           // 19267584 (dead after expand)
#define OFF_KWT   OFF_XT                // 737280, aliases xt (written after expand)
#define OFF_Y     ((size_t)19267584)    // 115605504  y2 [b][p][h] bf16
#define OFF_Z     ((size_t)134873088)   // 115605504  z2 [b][p][h] bf16
#define OFF_W1C   ((size_t)250478592)   // 3538944
#define OFF_W3C   ((size_t)254017536)   // 3538944
#define OFF_XMEAN ((size_t)257556480)   // 12288   (zeroed)
#define OFF_YSUM  ((size_t)257568768)   // 73728   (zeroed)
#define OFF_R1    ((size_t)257642496)   // 1024
#define OFF_RBLK  ((size_t)257643520)   // 1024
#define OFF_R2    ((size_t)257644544)   // 1024
#define OFF_SC1   ((size_t)257645568)   // 2304
#define OFF_BI1   ((size_t)257647872)   // 2304
#define OFF_SC2   ((size_t)257650176)   // 2304
#define OFF_BI2   ((size_t)257652480)   // 2304
#define OFF_SC3   ((size_t)257654784)   // 384
#define OFF_BI3   ((size_t)257655168)   // 384

extern "C" void kernel_launch(void* const* d_in, const int* in_sizes, int n_in,
                              void* d_out, int out_size, void* d_ws, size_t ws_size,
                              hipStream_t stream) {
  const float* x   = (const float*)d_in[0];
  const float* wr1 = (const float*)d_in[1];
  const float* br1 = (const float*)d_in[2];
  const float* w1  = (const float*)d_in[3];
  const float* g1  = (const float*)d_in[4];
  const float* bt1 = (const float*)d_in[5];
  const float* m1  = (const float*)d_in[6];
  const float* v1  = (const float*)d_in[7];
  const float* wr2 = (const float*)d_in[8];
  const float* br2 = (const float*)d_in[9];
  const float* w2  = (const float*)d_in[10];
  const float* g2  = (const float*)d_in[11];
  const float* bt2 = (const float*)d_in[12];
  const float* m2  = (const float*)d_in[13];
  const float* v2  = (const float*)d_in[14];
  const float* w3  = (const float*)d_in[15];
  const float* g3  = (const float*)d_in[16];
  const float* bt3 = (const float*)d_in[17];
  const float* m3  = (const float*)d_in[18];
  const float* v3  = (const float*)d_in[19];
  const float* wr3 = (const float*)d_in[20];
  const float* br3 = (const float*)d_in[21];
  float* out = (float*)d_out;
  char* ws = (char*)d_ws;

  unsigned short* xt   = (unsigned short*)(ws + OFF_XT);
  unsigned short* y2   = (unsigned short*)(ws + OFF_Y);
  unsigned short* z2   = (unsigned short*)(ws + OFF_Z);
  unsigned short* w1c  = (unsigned short*)(ws + OFF_W1C);
  unsigned short* w3c  = (unsigned short*)(ws + OFF_W3C);
  float* xmean = (float*)(ws + OFF_XMEAN);
  float* ysum  = (float*)(ws + OFF_YSUM);
  float* r1    = (float*)(ws + OFF_R1);
  float* rblk  = (float*)(ws + OFF_RBLK);
  float* r2    = (float*)(ws + OFF_R2);
  float* sc1   = (float*)(ws + OFF_SC1);
  float* bi1   = (float*)(ws + OFF_BI1);
  float* sc2   = (float*)(ws + OFF_SC2);
  float* bi2   = (float*)(ws + OFF_BI2);
  float* sc3   = (float*)(ws + OFF_SC3);
  float* bi3   = (float*)(ws + OFF_BI3);
  float* kwt   = (float*)(ws + OFF_KWT);

  hipMemsetAsync(ws + OFF_XMEAN, 0, 12288 + 73728, stream);

  k_transpose<<<32 * 49, 256, 0, stream>>>(x, xt, xmean);
  k_router1<<<512, 64, 0, stream>>>(xmean, wr1, br1, wr3, br3, r1, rblk);
  k_bnprep<<<5, 256, 0, stream>>>(g1, bt1, m1, v1, g2, bt2, m2, v2, g3, bt3, m3, v3,
                                  sc1, bi1, sc2, bi2, sc3, bi3);
  k_mixw<<<432, 256, 0, stream>>>(w1, r1, w1c, w3, rblk, w3c);
  k_expand3<<<dim3(49, 3, 32), 256, 0, stream>>>(xt, w1c, sc1, bi1, y2, ysum);
  k_router2<<<256, 64, 0, stream>>>(ysum, wr2, br2, r2);
  k_kwmix2<<<72, 256, 0, stream>>>(r2, w2, sc2, bi2, kwt);
  k_dwise5<<<1008, 256, 0, stream>>>(y2, kwt, z2);
  k_project4<<<dim3(28, 1, 32), 384, 0, stream>>>(z2, w3c, sc3, bi3, x, out);
}

// Round 7
// 321.925 us; speedup vs baseline: 1.0323x; 1.0323x over previous
//
#include <hip/hip_runtime.h>
#include <hip/hip_bf16.h>

#define B_   32
#define CIN  96
#define COUT 96
#define NP   3136
#define NE   8
#define HIDD 576

typedef short bf16x8 __attribute__((ext_vector_type(8)));
typedef float f32x4 __attribute__((ext_vector_type(4)));

__device__ __forceinline__ unsigned short f2bf(float f) {
  __hip_bfloat16 h = __float2bfloat16(f);
  unsigned short u; __builtin_memcpy(&u, &h, 2); return u;
}
__device__ __forceinline__ float bf2f(unsigned short u) {
  unsigned int v = ((unsigned int)u) << 16;
  float f; __builtin_memcpy(&f, &v, 4); return f;
}
__device__ __forceinline__ float u2f(unsigned int v) {
  float f; __builtin_memcpy(&f, &v, 4); return f;
}

// ---------------- kernel 1: transpose x -> x_t[b][p][c] bf16, + partial sums -
// xpart[b][pt][c] = sum over 64 pixels of tile pt (write-once, no init needed)
__global__ __launch_bounds__(256) void k_transpose(const float* __restrict__ x,
                                                   unsigned short* __restrict__ xt,
                                                   float* __restrict__ xpart) {
  __shared__ float tile[CIN][65];
  int bi = blockIdx.x; int b = bi / 49, pt = bi % 49; int p0 = pt * 64;
  int t = threadIdx.x;
  for (int j = t; j < CIN * 64; j += 256) {
    int c = j >> 6, pi = j & 63;
    tile[c][pi] = x[((size_t)(b * CIN + c)) * NP + p0 + pi];
  }
  __syncthreads();
  if (t < CIN) {
    float s = 0.f;
    for (int i = 0; i < 64; ++i) s += tile[t][i];
    xpart[((size_t)(b * 49 + pt)) * CIN + t] = s;
  }
  for (int j = t; j < 64 * CIN; j += 256) {
    int p = j / CIN, c = j % CIN;
    xt[((size_t)(b * NP + p0 + p)) * CIN + c] = f2bf(tile[c][p]);
  }
}

// ---------------- kernel 2: fused routers r1/rblk + BN scale/bias prep -------
// blocks 0..511: router tasks (64 thr); blocks 512..531: bnprep (1248 items)
__global__ __launch_bounds__(64) void k_front(const float* __restrict__ xpart,
    const float* __restrict__ wr1, const float* __restrict__ br1,
    const float* __restrict__ wr3, const float* __restrict__ br3,
    float* __restrict__ r1, float* __restrict__ rblk,
    const float* g1, const float* bt1, const float* m1, const float* v1,
    const float* g2, const float* bt2, const float* m2, const float* v2,
    const float* g3, const float* bt3, const float* m3, const float* v3,
    float* sc1, float* bi1, float* sc2, float* bi2, float* sc3, float* bi3) {
  int bi = blockIdx.x; int lane = threadIdx.x;
  if (bi < 512) {
    const float* wr; const float* br; float* dst; int id;
    if (bi < 256) { wr = wr1; br = br1; dst = r1;   id = bi; }
    else          { wr = wr3; br = br3; dst = rblk; id = bi - 256; }
    int b = id >> 3, e = id & 7;
    float s = 0.f;
    for (int c = lane; c < CIN; c += 64) {
      const float* xp = xpart + (size_t)b * 49 * CIN + c;
      float xm = 0.f;
#pragma unroll 7
      for (int k = 0; k < 49; ++k) xm += xp[k * CIN];
      s += xm * (1.0f / NP) * wr[e * CIN + c];
    }
    s += __shfl_xor(s, 1);  s += __shfl_xor(s, 2);  s += __shfl_xor(s, 4);
    s += __shfl_xor(s, 8);  s += __shfl_xor(s, 16); s += __shfl_xor(s, 32);
    if (lane == 0) dst[id] = 1.0f / (1.0f + __expf(-(s + br[e])));
  } else {
    int i = (bi - 512) * 64 + lane;
    if (i < HIDD) {
      float s = g1[i] * rsqrtf(v1[i] + 1e-5f); sc1[i] = s; bi1[i] = bt1[i] - m1[i] * s;
    } else if (i < 2 * HIDD) {
      int c = i - HIDD;
      float s = g2[c] * rsqrtf(v2[c] + 1e-5f); sc2[c] = s; bi2[c] = bt2[c] - m2[c] * s;
    } else if (i < 2 * HIDD + COUT) {
      int c = i - 2 * HIDD;
      float s = g3[c] * rsqrtf(v3[c] + 1e-5f); sc3[c] = s; bi3[c] = bt3[c] - m3[c] * s;
    }
  }
}

// ---------------- kernel 3: mix expert weights -> bf16 -----------------------
__global__ __launch_bounds__(256) void k_mixw(
    const float* __restrict__ w1, const float* __restrict__ r1, unsigned short* __restrict__ w1c,
    const float* __restrict__ w3, const float* __restrict__ rblk, unsigned short* __restrict__ w3c) {
  __shared__ float rsh[256];
  int bi = blockIdx.x; int t = threadIdx.x;
  const float* w; const float* r; unsigned short* dst; int oc0;
  if (bi < 216) { w = w1; r = r1;   dst = w1c; oc0 = bi * 256; }
  else          { w = w3; r = rblk; dst = w3c; oc0 = (bi - 216) * 256; }
  rsh[t] = r[t];
  __syncthreads();
  int oc = oc0 + t;
  float wv[NE];
#pragma unroll
  for (int e = 0; e < NE; ++e) wv[e] = w[(size_t)e * 55296 + oc];
  for (int b = 0; b < B_; ++b) {
    float a = 0.f;
#pragma unroll
    for (int e = 0; e < NE; ++e) a += rsh[b * 8 + e] * wv[e];
    dst[(size_t)b * 55296 + oc] = f2bf(a);
  }
}

// ---------------- kernel 4: expand GEMM + BN + ReLU6, y in [b][p][h] ---------
// Writes yspart[b][pt][o] (per-tile row sums, write-once; replaces atomics)
__global__ __launch_bounds__(256) void k_expand2(const unsigned short* __restrict__ xt,
    const unsigned short* __restrict__ w1c, const float* __restrict__ sc1,
    const float* __restrict__ bi1, unsigned short* __restrict__ y2,
    float* __restrict__ yspart) {
  __shared__ unsigned short As[64 * 104];   // w1c tile; reused as transpose buf T[64][72]
  __shared__ unsigned short Bs[64 * 104];   // xt tile
  int t = threadIdx.x;
  int pt = blockIdx.x;
  int p0 = pt * 64, o0 = blockIdx.y * 64, b = blockIdx.z;
  const unsigned short* ag = w1c + (size_t)b * 55296 + (size_t)o0 * 96;
  const unsigned short* bg = xt + ((size_t)b * NP + p0) * 96;
  for (int j = t; j < 768; j += 256) {
    int r = j / 12, ch = j % 12;
    *(int4*)(As + r * 104 + ch * 8) = *(const int4*)(ag + r * 96 + ch * 8);
    *(int4*)(Bs + r * 104 + ch * 8) = *(const int4*)(bg + r * 96 + ch * 8);
  }
  __syncthreads();
  int lane = t & 63, wv = t >> 6;
  int m = lane & 15, q = lane >> 4;
  f32x4 acc[4];
#pragma unroll
  for (int nt = 0; nt < 4; ++nt) acc[nt] = 0.f;
#pragma unroll
  for (int kk = 0; kk < 3; ++kk) {
    bf16x8 af = *(const bf16x8*)(As + (wv * 16 + m) * 104 + kk * 32 + q * 8);
#pragma unroll
    for (int nt = 0; nt < 4; ++nt) {
      bf16x8 bfb = *(const bf16x8*)(Bs + (nt * 16 + m) * 104 + kk * 32 + q * 8);
      acc[nt] = __builtin_amdgcn_mfma_f32_16x16x32_bf16(af, bfb, acc[nt], 0, 0, 0);
    }
  }
  __syncthreads();   // all LDS reads done; As is now free for reuse
  float sc[4], bb[4];
#pragma unroll
  for (int i = 0; i < 4; ++i) {
    int o = o0 + wv * 16 + q * 4 + i;
    sc[i] = sc1[o]; bb[i] = bi1[o];
  }
  float rs[4] = {0.f, 0.f, 0.f, 0.f};
  unsigned short* T = As;   // T stride 72 u16
#pragma unroll
  for (int nt = 0; nt < 4; ++nt) {
    unsigned short pk[4];
#pragma unroll
    for (int i = 0; i < 4; ++i) {
      float v = acc[nt][i] * sc[i] + bb[i];
      v = fminf(fmaxf(v, 0.f), 6.f);
      rs[i] += v;
      pk[i] = f2bf(v);
    }
    uint2 pv; __builtin_memcpy(&pv, pk, 8);
    *(uint2*)(T + (nt * 16 + m) * 72 + wv * 16 + q * 4) = pv;
  }
#pragma unroll
  for (int i = 0; i < 4; ++i) {
    float r = rs[i];
    r += __shfl_xor(r, 1); r += __shfl_xor(r, 2);
    r += __shfl_xor(r, 4); r += __shfl_xor(r, 8);
    if (m == 0)
      yspart[((size_t)b * 49 + pt) * HIDD + o0 + wv * 16 + q * 4 + i] = r;
  }
  __syncthreads();
  for (int j = t; j < 512; j += 256) {
    int r = j >> 3, ch = j & 7;
    *(int4*)(y2 + ((size_t)(b * NP + p0 + r)) * 576 + o0 + ch * 8) =
        *(const int4*)(T + r * 72 + ch * 8);
  }
}

// ---------------- kernel 5: fused router2 + tap premix (one block per batch) -
// kwt[b][k][c] = (Σ_e r2[b][e] w2[e][c][k]) * sc2[c];  kwt[b][9][c] = bias
__global__ __launch_bounds__(256) void k_mid(const float* __restrict__ yspart,
    const float* __restrict__ wr2, const float* __restrict__ br2,
    const float* __restrict__ w2, const float* __restrict__ sc2,
    const float* __restrict__ bi2, float* __restrict__ kwt) {
  __shared__ float ysum_l[HIDD];
  __shared__ float r2_l[NE];
  int b = blockIdx.x, t = threadIdx.x;
  const float* yp = yspart + (size_t)b * 49 * HIDD;
  for (int c = t; c < HIDD; c += 256) {
    float s = 0.f;
#pragma unroll 7
    for (int k = 0; k < 49; ++k) s += yp[k * HIDD + c];
    ysum_l[c] = s;
  }
  __syncthreads();
  int wv = t >> 6, lane = t & 63;
  for (int e = wv; e < NE; e += 4) {
    float s = 0.f;
    for (int h = lane; h < HIDD; h += 64)
      s += ysum_l[h] * (1.0f / NP) * wr2[e * HIDD + h];
    s += __shfl_xor(s, 1);  s += __shfl_xor(s, 2);  s += __shfl_xor(s, 4);
    s += __shfl_xor(s, 8);  s += __shfl_xor(s, 16); s += __shfl_xor(s, 32);
    if (lane == 0) r2_l[e] = 1.0f / (1.0f + __expf(-(s + br2[e])));
  }
  __syncthreads();
  float rr[NE];
#pragma unroll
  for (int e = 0; e < NE; ++e) rr[e] = r2_l[e];
  for (int c = t; c < HIDD; c += 256) {
    float sc = sc2[c];
    float* dst = kwt + (size_t)b * 5760 + c;
#pragma unroll
    for (int k = 0; k < 9; ++k) {
      float s = 0.f;
#pragma unroll
      for (int e = 0; e < NE; ++e) s += rr[e] * w2[((size_t)e * HIDD + c) * 9 + k];
      dst[k * 576] = s * sc;
    }
    dst[9 * 576] = bi2[c];
  }
}

// ---------------- kernel 6: depthwise 3x3 — 4ch x 2 rows x 28 cols / thread --
__device__ __forceinline__ f32x4 cvt4(uint2 v) {
  f32x4 r;
  r[0] = u2f(v.x << 16); r[1] = u2f(v.x & 0xffff0000u);
  r[2] = u2f(v.y << 16); r[3] = u2f(v.y & 0xffff0000u);
  return r;
}
__device__ __forceinline__ uint2 pack4(f32x4 v) {
  uint2 r;
  r.x = (unsigned)f2bf(v[0]) | ((unsigned)f2bf(v[1]) << 16);
  r.y = (unsigned)f2bf(v[2]) | ((unsigned)f2bf(v[3]) << 16);
  return r;
}
__device__ __forceinline__ f32x4 clamp6(f32x4 v) {
#pragma unroll
  for (int i = 0; i < 4; ++i) v[i] = fminf(fmaxf(v[i], 0.f), 6.f);
  return v;
}

__global__ __launch_bounds__(256) void k_dwise5(const unsigned short* __restrict__ y2,
    const float* __restrict__ kwt, unsigned short* __restrict__ z2) {
  int id = blockIdx.x * 256 + threadIdx.x;   // 32 b * 28 hp * 2 wh * 144 cq = 258048
  int cg = id % 144; int rest = id / 144;
  int wh = rest & 1; rest >>= 1;
  int hp = rest % 28; int b = rest / 28;
  int c = cg * 4, h0 = hp * 2, wsrt = wh * 28;
  const float* kp = kwt + (size_t)b * 5760 + c;
  f32x4 tk[9], tb;
#pragma unroll
  for (int k = 0; k < 9; ++k) tk[k] = *(const f32x4*)(kp + k * 576);
  tb = *(const f32x4*)(kp + 9 * 576);
  bool ok0 = (hp > 0), ok3 = (hp < 27);
  int r0 = ok0 ? (h0 - 1) : h0;
  int r3 = ok3 ? (h0 + 2) : (h0 + 1);
  const unsigned short* rowp[4];
  rowp[0] = y2 + ((size_t)(b * NP + r0 * 56)) * 576 + c;
  rowp[1] = y2 + ((size_t)(b * NP + h0 * 56)) * 576 + c;
  rowp[2] = y2 + ((size_t)(b * NP + (h0 + 1) * 56)) * 576 + c;
  rowp[3] = y2 + ((size_t)(b * NP + r3 * 56)) * 576 + c;
  bool rok[4] = {ok0, true, true, ok3};
  unsigned short* zr0 = z2 + ((size_t)(b * NP + h0 * 56)) * 576 + c;
  unsigned short* zr1 = zr0 + (size_t)56 * 576;

  f32x4 P[4], C[4], N[4];

#define LOADCOL(D, col) do {                                           \
    _Pragma("unroll") for (int j = 0; j < 4; ++j) {                    \
      uint2 raw; raw.x = 0u; raw.y = 0u;                               \
      if ((unsigned)(col) < 56u && rok[j])                             \
        raw = *(const uint2*)(rowp[j] + (size_t)(col) * 576);          \
      D[j] = cvt4(raw);                                                \
    } } while (0)

#define DSTEP(PP, CC, NN, wcur) do {                                   \
    f32x4 o0 = tb, o1 = tb;                                            \
    _Pragma("unroll") for (int jj = 0; jj < 3; ++jj) {                 \
      o0 += PP[jj] * tk[jj * 3] + CC[jj] * tk[jj * 3 + 1] + NN[jj] * tk[jj * 3 + 2]; \
      o1 += PP[jj + 1] * tk[jj * 3] + CC[jj + 1] * tk[jj * 3 + 1] + NN[jj + 1] * tk[jj * 3 + 2]; \
    }                                                                  \
    *(uint2*)(zr0 + (size_t)(wcur) * 576) = pack4(clamp6(o0));         \
    *(uint2*)(zr1 + (size_t)(wcur) * 576) = pack4(clamp6(o1));         \
    LOADCOL(PP, (wcur) + 2);                                           \
  } while (0)

  LOADCOL(P, wsrt - 1);
  LOADCOL(C, wsrt);
  LOADCOL(N, wsrt + 1);
  for (int w = wsrt; w < wsrt + 27; w += 3) {
    DSTEP(P, C, N, w);
    DSTEP(C, N, P, w + 1);
    DSTEP(N, P, C, w + 2);
  }
  DSTEP(P, C, N, wsrt + 27);
#undef DSTEP
#undef LOADCOL
}

// ---------------- kernel 7: project GEMM + BN + residual (z in [p][h]) -------
__global__ __launch_bounds__(384) void k_project4(const unsigned short* __restrict__ z2,
    const unsigned short* __restrict__ w3c, const float* __restrict__ sc3,
    const float* __restrict__ bi3, const float* __restrict__ x, float* __restrict__ out) {
  __shared__ unsigned short As[96 * 72];
  __shared__ unsigned short Bs[112 * 72];
  int t = threadIdx.x;
  int p0 = blockIdx.x * 112, b = blockIdx.z;
  const unsigned short* ag = w3c + (size_t)b * 55296;
  const unsigned short* zb = z2 + ((size_t)(b * NP + p0)) * 576;
  int lane = t & 63, wv = t >> 6;
  int m = lane & 15, q = lane >> 4;
  f32x4 acc[7];
#pragma unroll
  for (int nt = 0; nt < 7; ++nt) acc[nt] = 0.f;
  for (int c0 = 0; c0 < HIDD; c0 += 64) {
    __syncthreads();
    for (int j = t; j < 768; j += 384) {
      int r = j >> 3, ch = j & 7;
      *(int4*)(As + r * 72 + ch * 8) = *(const int4*)(ag + (size_t)r * 576 + c0 + ch * 8);
    }
    for (int j = t; j < 896; j += 384) {
      int r = j >> 3, ch = j & 7;
      *(int4*)(Bs + r * 72 + ch * 8) = *(const int4*)(zb + (size_t)r * 576 + c0 + ch * 8);
    }
    __syncthreads();
#pragma unroll
    for (int kk = 0; kk < 2; ++kk) {
      bf16x8 af = *(const bf16x8*)(As + (wv * 16 + m) * 72 + kk * 32 + q * 8);
#pragma unroll
      for (int nt = 0; nt < 7; ++nt) {
        bf16x8 bfb = *(const bf16x8*)(Bs + (nt * 16 + m) * 72 + kk * 32 + q * 8);
        acc[nt] = __builtin_amdgcn_mfma_f32_16x16x32_bf16(af, bfb, acc[nt], 0, 0, 0);
      }
    }
  }
#pragma unroll
  for (int i = 0; i < 4; ++i) {
    int o = wv * 16 + q * 4 + i;
    float sc = sc3[o], bb = bi3[o];
    size_t base = ((size_t)(b * COUT + o)) * NP + p0;
#pragma unroll
    for (int nt = 0; nt < 7; ++nt) {
      float v = acc[nt][i] * sc + bb + x[base + nt * 16 + m];
      out[base + nt * 16 + m] = v;
    }
  }
}

// ---------------- workspace layout (bytes) -----------------------------------
// xpart/yspart alias the z2 region (dead until k_dwise5); kwt aliases xt
// (dead after k_expand2). Total unchanged vs round 4-6 (~245.8 MiB).
#define OFF_XT     ((size_t)0)           // 19267584 (dead after expand)
#define OFF_KWT    OFF_XT                // 737280, aliases xt
#define OFF_Y      ((size_t)19267584)    // 115605504  y2 [b][p][h] bf16
#define OFF_Z      ((size_t)134873088)   // 115605504  z2 [b][p][h] bf16
#define OFF_XPART  OFF_Z                 // 602112, aliases z2 (dead before dwise)
#define OFF_YSPART (OFF_Z + 602112)      // 3612672, aliases z2 (dead before dwise)
#define OFF_W1C    ((size_t)250478592)   // 3538944
#define OFF_W3C    ((size_t)254017536)   // 3538944
#define OFF_R1     ((size_t)257642496)   // 1024
#define OFF_RBLK   ((size_t)257643520)   // 1024
#define OFF_SC1    ((size_t)257645568)   // 2304
#define OFF_BI1    ((size_t)257647872)   // 2304
#define OFF_SC2    ((size_t)257650176)   // 2304
#define OFF_BI2    ((size_t)257652480)   // 2304
#define OFF_SC3    ((size_t)257654784)   // 384
#define OFF_BI3    ((size_t)257655168)   // 384

extern "C" void kernel_launch(void* const* d_in, const int* in_sizes, int n_in,
                              void* d_out, int out_size, void* d_ws, size_t ws_size,
                              hipStream_t stream) {
  const float* x   = (const float*)d_in[0];
  const float* wr1 = (const float*)d_in[1];
  const float* br1 = (const float*)d_in[2];
  const float* w1  = (const float*)d_in[3];
  const float* g1  = (const float*)d_in[4];
  const float* bt1 = (const float*)d_in[5];
  const float* m1  = (const float*)d_in[6];
  const float* v1  = (const float*)d_in[7];
  const float* wr2 = (const float*)d_in[8];
  const float* br2 = (const float*)d_in[9];
  const float* w2  = (const float*)d_in[10];
  const float* g2  = (const float*)d_in[11];
  const float* bt2 = (const float*)d_in[12];
  const float* m2  = (const float*)d_in[13];
  const float* v2  = (const float*)d_in[14];
  const float* w3  = (const float*)d_in[15];
  const float* g3  = (const float*)d_in[16];
  const float* bt3 = (const float*)d_in[17];
  const float* m3  = (const float*)d_in[18];
  const float* v3  = (const float*)d_in[19];
  const float* wr3 = (const float*)d_in[20];
  const float* br3 = (const float*)d_in[21];
  float* out = (float*)d_out;
  char* ws = (char*)d_ws;

  unsigned short* xt     = (unsigned short*)(ws + OFF_XT);
  unsigned short* y2     = (unsigned short*)(ws + OFF_Y);
  unsigned short* z2     = (unsigned short*)(ws + OFF_Z);
  unsigned short* w1c    = (unsigned short*)(ws + OFF_W1C);
  unsigned short* w3c    = (unsigned short*)(ws + OFF_W3C);
  float* xpart  = (float*)(ws + OFF_XPART);
  float* yspart = (float*)(ws + OFF_YSPART);
  float* r1     = (float*)(ws + OFF_R1);
  float* rblk   = (float*)(ws + OFF_RBLK);
  float* sc1    = (float*)(ws + OFF_SC1);
  float* bi1    = (float*)(ws + OFF_BI1);
  float* sc2    = (float*)(ws + OFF_SC2);
  float* bi2    = (float*)(ws + OFF_BI2);
  float* sc3    = (float*)(ws + OFF_SC3);
  float* bi3    = (float*)(ws + OFF_BI3);
  float* kwt    = (float*)(ws + OFF_KWT);

  k_transpose<<<32 * 49, 256, 0, stream>>>(x, xt, xpart);
  k_front<<<532, 64, 0, stream>>>(xpart, wr1, br1, wr3, br3, r1, rblk,
                                  g1, bt1, m1, v1, g2, bt2, m2, v2, g3, bt3, m3, v3,
                                  sc1, bi1, sc2, bi2, sc3, bi3);
  k_mixw<<<432, 256, 0, stream>>>(w1, r1, w1c, w3, rblk, w3c);
  k_expand2<<<dim3(49, 9, 32), 256, 0, stream>>>(xt, w1c, sc1, bi1, y2, yspart);
  k_mid<<<32, 256, 0, stream>>>(yspart, wr2, br2, w2, sc2, bi2, kwt);
  k_dwise5<<<1008, 256, 0, stream>>>(y2, kwt, z2);
  k_project4<<<dim3(28, 1, 32), 384, 0, stream>>>(z2, w3c, sc3, bi3, x, out);
}